// Round 10
// baseline (1963.425 us; speedup 1.0000x reference)
//
#include <hip/hip_runtime.h>

// Problem constants: B=4, L=64, C=64, H=32, W=32
// BL = 256, HW = 1024, CHW = 65536, NIMG = B*L*C = 16384, NELEM = 16777216

#define NELEM 16777216
#define NIMG  16384

// ---------------- fully-unrolled register FFT-32 (radix-2 DIT) ----------------
template <bool INV>
__device__ __forceinline__ void fft32(float2 v[32]) {
#define SW(a, b) { float2 t_ = v[a]; v[a] = v[b]; v[b] = t_; }
  SW(1, 16) SW(2, 8)  SW(3, 24) SW(5, 20) SW(6, 12) SW(7, 28)
  SW(9, 18) SW(11, 26) SW(13, 22) SW(15, 30) SW(19, 25) SW(23, 29)
#undef SW
  constexpr float TC[16] = {
      1.0f, 0.9807852804032304f, 0.9238795325112867f, 0.8314696123025452f,
      0.7071067811865476f, 0.5555702330196022f, 0.3826834323650898f, 0.1950903220161283f,
      0.0f, -0.1950903220161283f, -0.3826834323650898f, -0.5555702330196022f,
      -0.7071067811865476f, -0.8314696123025452f, -0.9238795325112867f, -0.9807852804032304f};
  constexpr float TS[16] = {
      0.0f, 0.1950903220161283f, 0.3826834323650898f, 0.5555702330196022f,
      0.7071067811865476f, 0.8314696123025452f, 0.9238795325112867f, 0.9807852804032304f,
      1.0f, 0.9807852804032304f, 0.9238795325112867f, 0.8314696123025452f,
      0.7071067811865476f, 0.5555702330196022f, 0.3826834323650898f, 0.1950903220161283f};
#pragma unroll
  for (int s = 1; s <= 5; ++s) {
    const int len = 1 << s, half = len >> 1, tstep = 32 >> s;
#pragma unroll
    for (int i = 0; i < 32; i += len) {
#pragma unroll
      for (int j = 0; j < half; ++j) {
        const int k = j * tstep;
        const float wr = TC[k];
        const float wi = INV ? TS[k] : -TS[k];
        float2 b = v[i + j + half];
        float tr = wr * b.x - wi * b.y;
        float ti = wr * b.y + wi * b.x;
        float2 a = v[i + j];
        v[i + j] = make_float2(a.x + tr, a.y + ti);
        v[i + j + half] = make_float2(a.x - tr, a.y - ti);
      }
    }
  }
}

// ---------------- K1: channel mix (real x, complex Wb) -> A ----------------
// launch_bounds(256,4): 128-VGPR cap so acc[16][2] (64 VGPR) stays in VGPRs.
// Weights staged in LDS as float2; wave-uniform ds_read -> broadcast.
__global__ __launch_bounds__(256, 4) void kmix_b(const float* __restrict__ x,
                                                 float2* __restrict__ A,
                                                 const float* __restrict__ Wr,
                                                 const float* __restrict__ Wi) {
  __shared__ float2 w[4096];  // w[o*64+c] = (Wr[o][c], Wi[o][c]) = 32 KB
  const int t = threadIdx.x;
#pragma unroll
  for (int k = 0; k < 16; ++k) {
    int n = t + k * 256;
    w[n] = make_float2(Wr[n], Wi[n]);
  }
  __syncthreads();
  const int bl = blockIdx.x >> 3;
  const int p0 = (blockIdx.x & 7) << 7;                       // 128-position chunk
  const int pcol = (t & 63) * 2;                              // 2 consecutive positions
  const int obase = (t >> 6) * 16;                            // wave-uniform o-chunk
  const int rbase = bl * 65536 + p0 + pcol;

  float2 acc[16][2];
#pragma unroll
  for (int i = 0; i < 16; ++i) {
    acc[i][0] = make_float2(0.f, 0.f);
    acc[i][1] = make_float2(0.f, 0.f);
  }
#pragma unroll 4
  for (int c = 0; c < 64; ++c) {
    const float2 xv = *(const float2*)&x[rbase + c * 1024];   // 2 real inputs
#pragma unroll
    for (int i = 0; i < 16; ++i) {
      const float2 wc = w[(obase + i) * 64 + c];
      acc[i][0].x += wc.x * xv.x; acc[i][0].y += wc.y * xv.x;
      acc[i][1].x += wc.x * xv.y; acc[i][1].y += wc.y * xv.y;
    }
  }
#pragma unroll
  for (int i = 0; i < 16; ++i) {
    float4 st = make_float4(acc[i][0].x, acc[i][0].y, acc[i][1].x, acc[i][1].y);
    *(float4*)&A[rbase + (obase + i) * 1024] = st;
  }
}

// ---------------- K2: forward FFT2 per (b,l,c) image, epilogue (+bb)*gamma ----------------
__global__ __launch_bounds__(128) void kfft_fwd(float2* __restrict__ A,
                                                const float* __restrict__ pl,
                                                const float* __restrict__ bbr,
                                                const float* __restrict__ bbi) {
  __shared__ float2 tile[4 * 1056];  // 4 images, rows padded to 33 float2
  const int t = threadIdx.x;
  const int imgBase = blockIdx.x * 4096;  // float2 elements
#pragma unroll
  for (int k = 0; k < 32; ++k) {
    int n = t + k * 128;
    float2 v = A[imgBase + n];
    int img = n >> 10, rem = n & 1023;
    tile[img * 1056 + (rem >> 5) * 33 + (rem & 31)] = v;
  }
  __syncthreads();
  const int img = t >> 5, lane = t & 31;
  {
    float2 v[32];
    float2* row = &tile[img * 1056 + lane * 33];
#pragma unroll
    for (int j = 0; j < 32; ++j) v[j] = row[j];
    fft32<false>(v);
#pragma unroll
    for (int j = 0; j < 32; ++j) row[j] = v[j];
  }
  __syncthreads();
  {
    float2 v[32];
    float2* col = &tile[img * 1056 + lane];
#pragma unroll
    for (int j = 0; j < 32; ++j) v[j] = col[j * 33];
    fft32<false>(v);
#pragma unroll
    for (int j = 0; j < 32; ++j) col[j * 33] = v[j];
  }
  __syncthreads();
#pragma unroll
  for (int k = 0; k < 32; ++k) {
    int n = t + k * 128;
    int img2 = n >> 10, rem = n & 1023, r = rem >> 5, cc = rem & 31;
    int gimg = blockIdx.x * 4 + img2;
    int ch = gimg & 63;
    float2 v = tile[img2 * 1056 + r * 33 + cc];
    float g = expf(pl[(128 + ch) * 32 + r]);
    v.x = (v.x + bbr[ch]) * g;
    v.y = (v.y + bbi[ch]) * g;
    A[imgBase + n] = v;
  }
}

// ---------------- K3: linear recurrence over L, save last hidden ----------------
// MODE 0: out1 is real-part-only float array (tail == 262144 floats)
// MODE 1: out1 is interleaved complex (re,im) float2 array (tail == 524288 floats)
template <int MODE>
__global__ __launch_bounds__(256) void kscan(float2* __restrict__ A,
                                             const float* __restrict__ pl,
                                             float* __restrict__ out1) {
  const int gid = blockIdx.x * 256 + threadIdx.x;  // 0..262143  = (b, c, h, w)
  const int chw = gid & 65535;
  const int b = gid >> 16;
  const int c = chw >> 10, hh = (chw >> 5) & 31;
  const float nu = expf(pl[c * 32 + hh]);
  const float th = expf(pl[2048 + c * 32 + hh]);
  const float rad = expf(-nu);
  const float lr = rad * cosf(th);
  const float li = rad * sinf(th);
  const int base = b * 4194304 + chw;  // b * L*CHW
  float2 h = A[base];
#pragma unroll 4
  for (int l = 1; l < 64; ++l) {
    float2 v = A[base + l * 65536];
    float hx = lr * h.x - li * h.y + v.x;
    float hy = lr * h.y + li * h.x + v.y;
    h = make_float2(hx, hy);
    A[base + l * 65536] = h;
  }
  if (MODE == 0) {
    out1[gid] = h.x;  // real part only
  } else {
    ((float2*)out1)[gid] = h;  // interleaved complex64
  }
}

// ---------------- K4: channel mix with Wc in frequency domain (in place) ----------------
// Block owns full 64-channel column of 128 positions -> in-place safe (disjoint
// per block); __syncthreads() between last read and first write guards WAR.
__global__ __launch_bounds__(256, 4) void kmix_c(float2* __restrict__ A,
                                                 const float* __restrict__ Wr,
                                                 const float* __restrict__ Wi) {
  __shared__ float2 w[4096];  // 32 KB
  const int t = threadIdx.x;
#pragma unroll
  for (int k = 0; k < 16; ++k) {
    int n = t + k * 256;
    w[n] = make_float2(Wr[n], Wi[n]);
  }
  __syncthreads();
  const int bl = blockIdx.x >> 3;
  const int p0 = (blockIdx.x & 7) << 7;
  const int pcol = (t & 63) * 2;
  const int obase = (t >> 6) * 16;
  const int rbase = bl * 65536 + p0 + pcol;

  float2 acc[16][2];
#pragma unroll
  for (int i = 0; i < 16; ++i) {
    acc[i][0] = make_float2(0.f, 0.f);
    acc[i][1] = make_float2(0.f, 0.f);
  }
#pragma unroll 4
  for (int c = 0; c < 64; ++c) {
    const float4 xv = *(const float4*)&A[rbase + c * 1024];   // 2 complex inputs
#pragma unroll
    for (int i = 0; i < 16; ++i) {
      const float2 wc = w[(obase + i) * 64 + c];
      acc[i][0].x += wc.x * xv.x - wc.y * xv.y;
      acc[i][0].y += wc.x * xv.y + wc.y * xv.x;
      acc[i][1].x += wc.x * xv.z - wc.y * xv.w;
      acc[i][1].y += wc.x * xv.w + wc.y * xv.z;
    }
  }
  __syncthreads();  // all reads of this block's column done before any in-place write
#pragma unroll
  for (int i = 0; i < 16; ++i) {
    float4 st = make_float4(acc[i][0].x, acc[i][0].y, acc[i][1].x, acc[i][1].y);
    *(float4*)&A[rbase + (obase + i) * 1024] = st;
  }
}

// ---------------- K5: inverse FFT2 + bc + real + LayerNorm + residual ----------------
__global__ __launch_bounds__(128) void kfft_inv_ln(const float2* __restrict__ A,
                                                   const float* __restrict__ x,
                                                   const float* __restrict__ bcr,
                                                   const float* __restrict__ lnw,
                                                   const float* __restrict__ lnb,
                                                   float* __restrict__ out0) {
  __shared__ float2 tile[4 * 1056];
  const int t = threadIdx.x;
  const int imgBase = blockIdx.x * 4096;
#pragma unroll
  for (int k = 0; k < 32; ++k) {
    int n = t + k * 128;
    float2 v = A[imgBase + n];
    int img = n >> 10, rem = n & 1023;
    tile[img * 1056 + (rem >> 5) * 33 + (rem & 31)] = v;
  }
  __syncthreads();
  const int img = t >> 5, lane = t & 31;
  {
    float2 v[32];
    float2* row = &tile[img * 1056 + lane * 33];
#pragma unroll
    for (int j = 0; j < 32; ++j) v[j] = row[j];
    fft32<true>(v);
#pragma unroll
    for (int j = 0; j < 32; ++j) row[j] = v[j];
  }
  __syncthreads();
  float2 v[32];
  {
    float2* col = &tile[img * 1056 + lane];
#pragma unroll
    for (int j = 0; j < 32; ++j) v[j] = col[j * 33];
    fft32<true>(v);
  }
  const int gimg = blockIdx.x * 4 + img;
  const int ch = gimg & 63;
  const float bc = bcr[ch];
  float rr[32];
  float s1 = 0.f, s2 = 0.f;
#pragma unroll
  for (int r = 0; r < 32; ++r) {
    rr[r] = v[r].x * (1.0f / 1024.0f) + bc;
    s1 += rr[r];
    s2 += rr[r] * rr[r];
  }
#pragma unroll
  for (int m = 1; m < 32; m <<= 1) {
    s1 += __shfl_xor(s1, m, 64);
    s2 += __shfl_xor(s2, m, 64);
  }
  const float mu = s1 * (1.0f / 1024.0f);
  const float var = s2 * (1.0f / 1024.0f) - mu * mu;
  const float rs = rsqrtf(var + 1e-5f);
  const int obase = gimg * 1024;
#pragma unroll
  for (int r = 0; r < 32; ++r) {
    int sp = r * 32 + lane;
    out0[obase + sp] = (rr[r] - mu) * rs * lnw[sp] + lnb[sp] + x[obase + sp];
  }
}

extern "C" void kernel_launch(void* const* d_in, const int* in_sizes, int n_in,
                              void* d_out, int out_size, void* d_ws, size_t ws_size,
                              hipStream_t stream) {
  const float* x   = (const float*)d_in[0];
  const float* pl  = (const float*)d_in[1];
  const float* Wbr = (const float*)d_in[2];
  const float* Wbi = (const float*)d_in[3];
  const float* bbr = (const float*)d_in[4];
  const float* bbi = (const float*)d_in[5];
  const float* Wcr = (const float*)d_in[6];
  const float* Wci = (const float*)d_in[7];
  const float* bcr = (const float*)d_in[8];
  // d_in[9] = bc_i: dropped by taking real part
  const float* lnw = (const float*)d_in[10];
  const float* lnb = (const float*)d_in[11];

  float* out0 = (float*)d_out;
  float* out1 = (float*)d_out + NELEM;  // tail: last_hidden_out
  float2* A = (float2*)d_ws;            // 16,777,216 complex = 134 MB

  const int tail = out_size - NELEM;

  kmix_b<<<2048, 256, 0, stream>>>(x, A, Wbr, Wbi);
  kfft_fwd<<<4096, 128, 0, stream>>>(A, pl, bbr, bbi);
  if (tail == 262144) {
    kscan<0><<<1024, 256, 0, stream>>>(A, pl, out1);  // real part only
  } else {
    kscan<1><<<1024, 256, 0, stream>>>(A, pl, out1);  // interleaved complex
  }
  kmix_c<<<2048, 256, 0, stream>>>(A, Wcr, Wci);
  kfft_inv_ln<<<4096, 128, 0, stream>>>(A, x, bcr, lnw, lnb, out0);
}

// Round 13
// 561.097 us; speedup vs baseline: 3.4993x; 3.4993x over previous
//
#include <hip/hip_runtime.h>

// Problem constants: B=4, L=64, C=64, H=32, W=32
// BL = 256, HW = 1024, CHW = 65536, NIMG = B*L*C = 16384, NELEM = 16777216

#define NELEM 16777216
#define NIMG  16384

// ---------------- fully-unrolled register FFT-32 (radix-2 DIT) ----------------
template <bool INV>
__device__ __forceinline__ void fft32(float2 v[32]) {
#define SW(a, b) { float2 t_ = v[a]; v[a] = v[b]; v[b] = t_; }
  SW(1, 16) SW(2, 8)  SW(3, 24) SW(5, 20) SW(6, 12) SW(7, 28)
  SW(9, 18) SW(11, 26) SW(13, 22) SW(15, 30) SW(19, 25) SW(23, 29)
#undef SW
  constexpr float TC[16] = {
      1.0f, 0.9807852804032304f, 0.9238795325112867f, 0.8314696123025452f,
      0.7071067811865476f, 0.5555702330196022f, 0.3826834323650898f, 0.1950903220161283f,
      0.0f, -0.1950903220161283f, -0.3826834323650898f, -0.5555702330196022f,
      -0.7071067811865476f, -0.8314696123025452f, -0.9238795325112867f, -0.9807852804032304f};
  constexpr float TS[16] = {
      0.0f, 0.1950903220161283f, 0.3826834323650898f, 0.5555702330196022f,
      0.7071067811865476f, 0.8314696123025452f, 0.9238795325112867f, 0.9807852804032304f,
      1.0f, 0.9807852804032304f, 0.9238795325112867f, 0.8314696123025452f,
      0.7071067811865476f, 0.5555702330196022f, 0.3826834323650898f, 0.1950903220161283f};
#pragma unroll
  for (int s = 1; s <= 5; ++s) {
    const int len = 1 << s, half = len >> 1, tstep = 32 >> s;
#pragma unroll
    for (int i = 0; i < 32; i += len) {
#pragma unroll
      for (int j = 0; j < half; ++j) {
        const int k = j * tstep;
        const float wr = TC[k];
        const float wi = INV ? TS[k] : -TS[k];
        float2 b = v[i + j + half];
        float tr = wr * b.x - wi * b.y;
        float ti = wr * b.y + wi * b.x;
        float2 a = v[i + j];
        v[i + j] = make_float2(a.x + tr, a.y + ti);
        v[i + j + half] = make_float2(a.x - tr, a.y - ti);
      }
    }
  }
}

// ---------------- K1: channel mix (real x, complex Wb) -> A ----------------
// 512 threads = 8 waves; wave w owns output channels [8w, 8w+8); thread owns
// 2 positions. acc[8][2] float2 = 32 VGPR -> fits the 64-VGPR budget honestly.
// W staged in LDS; per-(i,c) address is wave-uniform -> broadcast ds_read.
__global__ __launch_bounds__(512) void kmix_b(const float* __restrict__ x,
                                              float2* __restrict__ A,
                                              const float* __restrict__ Wr,
                                              const float* __restrict__ Wi) {
  __shared__ float2 w[4096];  // w[o*64+c] = (Wr[o][c], Wi[o][c]) = 32 KB
  const int t = threadIdx.x;
#pragma unroll
  for (int k = 0; k < 8; ++k) {
    int n = t + k * 512;
    w[n] = make_float2(Wr[n], Wi[n]);
  }
  __syncthreads();
  const int bl = blockIdx.x >> 3;
  const int p0 = (blockIdx.x & 7) << 7;   // 128-position chunk
  const int pcol = (t & 63) * 2;          // 2 consecutive positions
  const int obase = (t >> 6) * 8;         // wave-uniform channel chunk
  const int rbase = bl * 65536 + p0 + pcol;

  float2 acc[8][2];
#pragma unroll
  for (int i = 0; i < 8; ++i) {
    acc[i][0] = make_float2(0.f, 0.f);
    acc[i][1] = make_float2(0.f, 0.f);
  }
#pragma unroll 4
  for (int c = 0; c < 64; ++c) {
    const float2 xv = *(const float2*)&x[rbase + c * 1024];   // 2 real inputs
#pragma unroll
    for (int i = 0; i < 8; ++i) {
      const float2 wc = w[(obase + i) * 64 + c];
      acc[i][0].x += wc.x * xv.x; acc[i][0].y += wc.y * xv.x;
      acc[i][1].x += wc.x * xv.y; acc[i][1].y += wc.y * xv.y;
    }
  }
#pragma unroll
  for (int i = 0; i < 8; ++i) {
    float4 st = make_float4(acc[i][0].x, acc[i][0].y, acc[i][1].x, acc[i][1].y);
    *(float4*)&A[rbase + (obase + i) * 1024] = st;
  }
}

// ---------------- K2: forward FFT2 per (b,l,c) image, epilogue (+bb)*gamma ----------------
__global__ __launch_bounds__(128) void kfft_fwd(float2* __restrict__ A,
                                                const float* __restrict__ pl,
                                                const float* __restrict__ bbr,
                                                const float* __restrict__ bbi) {
  __shared__ float2 tile[4 * 1056];  // 4 images, rows padded to 33 float2
  const int t = threadIdx.x;
  const int imgBase = blockIdx.x * 4096;  // float2 elements
#pragma unroll
  for (int k = 0; k < 32; ++k) {
    int n = t + k * 128;
    float2 v = A[imgBase + n];
    int img = n >> 10, rem = n & 1023;
    tile[img * 1056 + (rem >> 5) * 33 + (rem & 31)] = v;
  }
  __syncthreads();
  const int img = t >> 5, lane = t & 31;
  {
    float2 v[32];
    float2* row = &tile[img * 1056 + lane * 33];
#pragma unroll
    for (int j = 0; j < 32; ++j) v[j] = row[j];
    fft32<false>(v);
#pragma unroll
    for (int j = 0; j < 32; ++j) row[j] = v[j];
  }
  __syncthreads();
  {
    float2 v[32];
    float2* col = &tile[img * 1056 + lane];
#pragma unroll
    for (int j = 0; j < 32; ++j) v[j] = col[j * 33];
    fft32<false>(v);
#pragma unroll
    for (int j = 0; j < 32; ++j) col[j * 33] = v[j];
  }
  __syncthreads();
#pragma unroll
  for (int k = 0; k < 32; ++k) {
    int n = t + k * 128;
    int img2 = n >> 10, rem = n & 1023, r = rem >> 5, cc = rem & 31;
    int gimg = blockIdx.x * 4 + img2;
    int ch = gimg & 63;
    float2 v = tile[img2 * 1056 + r * 33 + cc];
    float g = expf(pl[(128 + ch) * 32 + r]);
    v.x = (v.x + bbr[ch]) * g;
    v.y = (v.y + bbi[ch]) * g;
    A[imgBase + n] = v;
  }
}

// ---------------- K3: linear recurrence over L, save last hidden ----------------
// MODE 0: out1 is real-part-only float array (tail == 262144 floats)
// MODE 1: out1 is interleaved complex (re,im) float2 array (tail == 524288 floats)
template <int MODE>
__global__ __launch_bounds__(256) void kscan(float2* __restrict__ A,
                                             const float* __restrict__ pl,
                                             float* __restrict__ out1) {
  const int gid = blockIdx.x * 256 + threadIdx.x;  // 0..262143  = (b, c, h, w)
  const int chw = gid & 65535;
  const int b = gid >> 16;
  const int c = chw >> 10, hh = (chw >> 5) & 31;
  const float nu = expf(pl[c * 32 + hh]);
  const float th = expf(pl[2048 + c * 32 + hh]);
  const float rad = expf(-nu);
  const float lr = rad * cosf(th);
  const float li = rad * sinf(th);
  const int base = b * 4194304 + chw;  // b * L*CHW
  float2 h = A[base];
#pragma unroll 4
  for (int l = 1; l < 64; ++l) {
    float2 v = A[base + l * 65536];
    float hx = lr * h.x - li * h.y + v.x;
    float hy = lr * h.y + li * h.x + v.y;
    h = make_float2(hx, hy);
    A[base + l * 65536] = h;
  }
  if (MODE == 0) {
    out1[gid] = h.x;  // real part only
  } else {
    ((float2*)out1)[gid] = h;  // interleaved complex64
  }
}

// ---------------- K4: channel mix with Wc in frequency domain (in place) ----------------
// Same 8-wave structure; complex input. Block owns full 64-channel column of
// 128 positions -> in-place safe (block-disjoint); __syncthreads() guards WAR.
__global__ __launch_bounds__(512) void kmix_c(float2* __restrict__ A,
                                              const float* __restrict__ Wr,
                                              const float* __restrict__ Wi) {
  __shared__ float2 w[4096];  // 32 KB
  const int t = threadIdx.x;
#pragma unroll
  for (int k = 0; k < 8; ++k) {
    int n = t + k * 512;
    w[n] = make_float2(Wr[n], Wi[n]);
  }
  __syncthreads();
  const int bl = blockIdx.x >> 3;
  const int p0 = (blockIdx.x & 7) << 7;
  const int pcol = (t & 63) * 2;
  const int obase = (t >> 6) * 8;
  const int rbase = bl * 65536 + p0 + pcol;

  float2 acc[8][2];
#pragma unroll
  for (int i = 0; i < 8; ++i) {
    acc[i][0] = make_float2(0.f, 0.f);
    acc[i][1] = make_float2(0.f, 0.f);
  }
#pragma unroll 4
  for (int c = 0; c < 64; ++c) {
    const float4 xv = *(const float4*)&A[rbase + c * 1024];   // 2 complex inputs
#pragma unroll
    for (int i = 0; i < 8; ++i) {
      const float2 wc = w[(obase + i) * 64 + c];
      acc[i][0].x += wc.x * xv.x - wc.y * xv.y;
      acc[i][0].y += wc.x * xv.y + wc.y * xv.x;
      acc[i][1].x += wc.x * xv.z - wc.y * xv.w;
      acc[i][1].y += wc.x * xv.w + wc.y * xv.z;
    }
  }
  __syncthreads();  // all reads of this block's column done before any in-place write
#pragma unroll
  for (int i = 0; i < 8; ++i) {
    float4 st = make_float4(acc[i][0].x, acc[i][0].y, acc[i][1].x, acc[i][1].y);
    *(float4*)&A[rbase + (obase + i) * 1024] = st;
  }
}

// ---------------- K5: inverse FFT2 + bc + real + LayerNorm + residual ----------------
__global__ __launch_bounds__(128) void kfft_inv_ln(const float2* __restrict__ A,
                                                   const float* __restrict__ x,
                                                   const float* __restrict__ bcr,
                                                   const float* __restrict__ lnw,
                                                   const float* __restrict__ lnb,
                                                   float* __restrict__ out0) {
  __shared__ float2 tile[4 * 1056];
  const int t = threadIdx.x;
  const int imgBase = blockIdx.x * 4096;
#pragma unroll
  for (int k = 0; k < 32; ++k) {
    int n = t + k * 128;
    float2 v = A[imgBase + n];
    int img = n >> 10, rem = n & 1023;
    tile[img * 1056 + (rem >> 5) * 33 + (rem & 31)] = v;
  }
  __syncthreads();
  const int img = t >> 5, lane = t & 31;
  {
    float2 v[32];
    float2* row = &tile[img * 1056 + lane * 33];
#pragma unroll
    for (int j = 0; j < 32; ++j) v[j] = row[j];
    fft32<true>(v);
#pragma unroll
    for (int j = 0; j < 32; ++j) row[j] = v[j];
  }
  __syncthreads();
  float2 v[32];
  {
    float2* col = &tile[img * 1056 + lane];
#pragma unroll
    for (int j = 0; j < 32; ++j) v[j] = col[j * 33];
    fft32<true>(v);
  }
  const int gimg = blockIdx.x * 4 + img;
  const int ch = gimg & 63;
  const float bc = bcr[ch];
  float rr[32];
  float s1 = 0.f, s2 = 0.f;
#pragma unroll
  for (int r = 0; r < 32; ++r) {
    rr[r] = v[r].x * (1.0f / 1024.0f) + bc;
    s1 += rr[r];
    s2 += rr[r] * rr[r];
  }
#pragma unroll
  for (int m = 1; m < 32; m <<= 1) {
    s1 += __shfl_xor(s1, m, 64);
    s2 += __shfl_xor(s2, m, 64);
  }
  const float mu = s1 * (1.0f / 1024.0f);
  const float var = s2 * (1.0f / 1024.0f) - mu * mu;
  const float rs = rsqrtf(var + 1e-5f);
  const int obase = gimg * 1024;
#pragma unroll
  for (int r = 0; r < 32; ++r) {
    int sp = r * 32 + lane;
    out0[obase + sp] = (rr[r] - mu) * rs * lnw[sp] + lnb[sp] + x[obase + sp];
  }
}

extern "C" void kernel_launch(void* const* d_in, const int* in_sizes, int n_in,
                              void* d_out, int out_size, void* d_ws, size_t ws_size,
                              hipStream_t stream) {
  const float* x   = (const float*)d_in[0];
  const float* pl  = (const float*)d_in[1];
  const float* Wbr = (const float*)d_in[2];
  const float* Wbi = (const float*)d_in[3];
  const float* bbr = (const float*)d_in[4];
  const float* bbi = (const float*)d_in[5];
  const float* Wcr = (const float*)d_in[6];
  const float* Wci = (const float*)d_in[7];
  const float* bcr = (const float*)d_in[8];
  // d_in[9] = bc_i: dropped by taking real part
  const float* lnw = (const float*)d_in[10];
  const float* lnb = (const float*)d_in[11];

  float* out0 = (float*)d_out;
  float* out1 = (float*)d_out + NELEM;  // tail: last_hidden_out
  float2* A = (float2*)d_ws;            // 16,777,216 complex = 134 MB

  const int tail = out_size - NELEM;

  kmix_b<<<2048, 512, 0, stream>>>(x, A, Wbr, Wbi);
  kfft_fwd<<<4096, 128, 0, stream>>>(A, pl, bbr, bbi);
  if (tail == 262144) {
    kscan<0><<<1024, 256, 0, stream>>>(A, pl, out1);  // real part only
  } else {
    kscan<1><<<1024, 256, 0, stream>>>(A, pl, out1);  // interleaved complex
  }
  kmix_c<<<2048, 512, 0, stream>>>(A, Wcr, Wci);
  kfft_inv_ln<<<4096, 128, 0, stream>>>(A, x, bcr, lnw, lnb, out0);
}

// Round 15
// 479.184 us; speedup vs baseline: 4.0974x; 1.1709x over previous
//
#include <hip/hip_runtime.h>

// Problem constants: B=4, L=64, C=64, H=32, W=32
// BL = 256, HW = 1024, CHW = 65536, NIMG = B*L*C = 16384, NELEM = 16777216

#define NELEM 16777216

// ---------------- fully-unrolled register FFT-32 (radix-2 DIT) ----------------
template <bool INV>
__device__ __forceinline__ void fft32(float2 v[32]) {
#define SW(a, b) { float2 t_ = v[a]; v[a] = v[b]; v[b] = t_; }
  SW(1, 16) SW(2, 8)  SW(3, 24) SW(5, 20) SW(6, 12) SW(7, 28)
  SW(9, 18) SW(11, 26) SW(13, 22) SW(15, 30) SW(19, 25) SW(23, 29)
#undef SW
  constexpr float TC[16] = {
      1.0f, 0.9807852804032304f, 0.9238795325112867f, 0.8314696123025452f,
      0.7071067811865476f, 0.5555702330196022f, 0.3826834323650898f, 0.1950903220161283f,
      0.0f, -0.1950903220161283f, -0.3826834323650898f, -0.5555702330196022f,
      -0.7071067811865476f, -0.8314696123025452f, -0.9238795325112867f, -0.9807852804032304f};
  constexpr float TS[16] = {
      0.0f, 0.1950903220161283f, 0.3826834323650898f, 0.5555702330196022f,
      0.7071067811865476f, 0.8314696123025452f, 0.9238795325112867f, 0.9807852804032304f,
      1.0f, 0.9807852804032304f, 0.9238795325112867f, 0.8314696123025452f,
      0.7071067811865476f, 0.5555702330196022f, 0.3826834323650898f, 0.1950903220161283f};
#pragma unroll
  for (int s = 1; s <= 5; ++s) {
    const int len = 1 << s, half = len >> 1, tstep = 32 >> s;
#pragma unroll
    for (int i = 0; i < 32; i += len) {
#pragma unroll
      for (int j = 0; j < half; ++j) {
        const int k = j * tstep;
        const float wr = TC[k];
        const float wi = INV ? TS[k] : -TS[k];
        float2 b = v[i + j + half];
        float tr = wr * b.x - wi * b.y;
        float ti = wr * b.y + wi * b.x;
        float2 a = v[i + j];
        v[i + j] = make_float2(a.x + tr, a.y + ti);
        v[i + j + half] = make_float2(a.x - tr, a.y - ti);
      }
    }
  }
}

// ---------------- K1: channel mix (real x, complex Wb) -> A ----------------
// 1024 threads = 16 waves; wave w owns 4 output channels; thread owns 4 positions.
// acc[4][4] float2 = 32 VGPR. Explicit fmaf; W broadcast from LDS.
__global__ __launch_bounds__(1024) void kmix_b(const float* __restrict__ x,
                                               float2* __restrict__ A,
                                               const float* __restrict__ Wr,
                                               const float* __restrict__ Wi) {
  __shared__ float2 w[4096];  // w[o*64+c] = (Wr[o][c], Wi[o][c]) = 32 KB
  const int t = threadIdx.x;
#pragma unroll
  for (int k = 0; k < 4; ++k) {
    int n = t + k * 1024;
    w[n] = make_float2(Wr[n], Wi[n]);
  }
  __syncthreads();
  const int bl = blockIdx.x >> 2;
  const int p0 = (blockIdx.x & 3) << 8;   // 256-position chunk
  const int pcol = (t & 63) * 4;          // 4 consecutive positions
  const int obase = (t >> 6) * 4;         // wave-uniform channel chunk (16 waves x 4)
  const int rbase = bl * 65536 + p0 + pcol;

  float2 acc[4][4];
#pragma unroll
  for (int i = 0; i < 4; ++i)
#pragma unroll
    for (int p = 0; p < 4; ++p) acc[i][p] = make_float2(0.f, 0.f);

#pragma unroll 4
  for (int c = 0; c < 64; ++c) {
    const float4 xv = *(const float4*)&x[rbase + c * 1024];   // 4 real inputs
    const float xs0 = xv.x, xs1 = xv.y, xs2 = xv.z, xs3 = xv.w;
#pragma unroll
    for (int i = 0; i < 4; ++i) {
      const float2 wc = w[(obase + i) * 64 + c];
      acc[i][0].x = fmaf(wc.x, xs0, acc[i][0].x); acc[i][0].y = fmaf(wc.y, xs0, acc[i][0].y);
      acc[i][1].x = fmaf(wc.x, xs1, acc[i][1].x); acc[i][1].y = fmaf(wc.y, xs1, acc[i][1].y);
      acc[i][2].x = fmaf(wc.x, xs2, acc[i][2].x); acc[i][2].y = fmaf(wc.y, xs2, acc[i][2].y);
      acc[i][3].x = fmaf(wc.x, xs3, acc[i][3].x); acc[i][3].y = fmaf(wc.y, xs3, acc[i][3].y);
    }
  }
#pragma unroll
  for (int i = 0; i < 4; ++i) {
    const int wb = rbase + (obase + i) * 1024;
    *(float4*)&A[wb]     = make_float4(acc[i][0].x, acc[i][0].y, acc[i][1].x, acc[i][1].y);
    *(float4*)&A[wb + 2] = make_float4(acc[i][2].x, acc[i][2].y, acc[i][3].x, acc[i][3].y);
  }
}

// ---------------- K2: forward FFT2 per (b,l,c) image, epilogue (+bb)*gamma ----------------
__global__ __launch_bounds__(128) void kfft_fwd(float2* __restrict__ A,
                                                const float* __restrict__ pl,
                                                const float* __restrict__ bbr,
                                                const float* __restrict__ bbi) {
  __shared__ float2 tile[4 * 1056];  // 4 images, rows padded to 33 float2
  const int t = threadIdx.x;
  const int imgBase = blockIdx.x * 4096;
#pragma unroll
  for (int k = 0; k < 32; ++k) {
    int n = t + k * 128;
    float2 v = A[imgBase + n];
    int img = n >> 10, rem = n & 1023;
    tile[img * 1056 + (rem >> 5) * 33 + (rem & 31)] = v;
  }
  __syncthreads();
  const int img = t >> 5, lane = t & 31;
  {
    float2 v[32];
    float2* row = &tile[img * 1056 + lane * 33];
#pragma unroll
    for (int j = 0; j < 32; ++j) v[j] = row[j];
    fft32<false>(v);
#pragma unroll
    for (int j = 0; j < 32; ++j) row[j] = v[j];
  }
  __syncthreads();
  {
    float2 v[32];
    float2* col = &tile[img * 1056 + lane];
#pragma unroll
    for (int j = 0; j < 32; ++j) v[j] = col[j * 33];
    fft32<false>(v);
#pragma unroll
    for (int j = 0; j < 32; ++j) col[j * 33] = v[j];
  }
  __syncthreads();
#pragma unroll
  for (int k = 0; k < 32; ++k) {
    int n = t + k * 128;
    int img2 = n >> 10, rem = n & 1023, r = rem >> 5, cc = rem & 31;
    int gimg = blockIdx.x * 4 + img2;
    int ch = gimg & 63;
    float2 v = tile[img2 * 1056 + r * 33 + cc];
    float g = expf(pl[(128 + ch) * 32 + r]);
    v.x = (v.x + bbr[ch]) * g;
    v.y = (v.y + bbi[ch]) * g;
    A[imgBase + n] = v;
  }
}

// ---------------- K3: linear recurrence over L, save last hidden ----------------
template <int MODE>
__global__ __launch_bounds__(256) void kscan(float2* __restrict__ A,
                                             const float* __restrict__ pl,
                                             float* __restrict__ out1) {
  const int gid = blockIdx.x * 256 + threadIdx.x;  // (b, c, h, w)
  const int chw = gid & 65535;
  const int b = gid >> 16;
  const int c = chw >> 10, hh = (chw >> 5) & 31;
  const float nu = expf(pl[c * 32 + hh]);
  const float th = expf(pl[2048 + c * 32 + hh]);
  const float rad = expf(-nu);
  const float lr = rad * cosf(th);
  const float li = rad * sinf(th);
  const int base = b * 4194304 + chw;
  float2 h = A[base];
#pragma unroll 4
  for (int l = 1; l < 64; ++l) {
    float2 v = A[base + l * 65536];
    float hx = lr * h.x - li * h.y + v.x;
    float hy = lr * h.y + li * h.x + v.y;
    h = make_float2(hx, hy);
    A[base + l * 65536] = h;
  }
  if (MODE == 0) {
    out1[gid] = h.x;
  } else {
    ((float2*)out1)[gid] = h;
  }
}

// ---------------- K4: inverse FFT2 per image, in place (unnormalized; 1/1024 folded into Wc) ----------------
__global__ __launch_bounds__(128) void kfft_inv(float2* __restrict__ A) {
  __shared__ float2 tile[4 * 1056];
  const int t = threadIdx.x;
  const int imgBase = blockIdx.x * 4096;
#pragma unroll
  for (int k = 0; k < 32; ++k) {
    int n = t + k * 128;
    float2 v = A[imgBase + n];
    int img = n >> 10, rem = n & 1023;
    tile[img * 1056 + (rem >> 5) * 33 + (rem & 31)] = v;
  }
  __syncthreads();
  const int img = t >> 5, lane = t & 31;
  {
    float2 v[32];
    float2* row = &tile[img * 1056 + lane * 33];
#pragma unroll
    for (int j = 0; j < 32; ++j) v[j] = row[j];
    fft32<true>(v);
#pragma unroll
    for (int j = 0; j < 32; ++j) row[j] = v[j];
  }
  __syncthreads();
  {
    float2 v[32];
    float2* col = &tile[img * 1056 + lane];
#pragma unroll
    for (int j = 0; j < 32; ++j) v[j] = col[j * 33];
    fft32<true>(v);
#pragma unroll
    for (int j = 0; j < 32; ++j) col[j * 33] = v[j];
  }
  __syncthreads();
#pragma unroll
  for (int k = 0; k < 32; ++k) {
    int n = t + k * 128;
    int img2 = n >> 10, rem = n & 1023;
    A[imgBase + n] = tile[img2 * 1056 + (rem >> 5) * 33 + (rem & 31)];
  }
}

// ---------------- K5: REAL channel mix after ifft: out0_pre = Re(Wc . p)/1024 + bc_r ----------------
// Half the FLOPs of the complex mix (we only need the real part).
// 512 threads = 8 waves x 8 channels; thread owns 4 positions; acc[8][4] float = 32 VGPR.
// Weights staged in LDS pre-scaled: (Wcr/1024, -Wci/1024).
__global__ __launch_bounds__(512) void kmix_cr(const float2* __restrict__ A,
                                               float* __restrict__ out0,
                                               const float* __restrict__ Wr,
                                               const float* __restrict__ Wi,
                                               const float* __restrict__ bcr) {
  __shared__ float2 w[4096];  // 32 KB
  const int t = threadIdx.x;
  constexpr float S = 1.0f / 1024.0f;
#pragma unroll
  for (int k = 0; k < 8; ++k) {
    int n = t + k * 512;
    w[n] = make_float2(Wr[n] * S, -Wi[n] * S);
  }
  __syncthreads();
  const int bl = blockIdx.x >> 2;
  const int p0 = (blockIdx.x & 3) << 8;   // 256-position chunk
  const int pcol = (t & 63) * 4;          // 4 consecutive positions
  const int obase = (t >> 6) * 8;         // wave-uniform channel chunk (8 waves x 8)
  const int rbase = bl * 65536 + p0 + pcol;

  float acc[8][4];
#pragma unroll
  for (int i = 0; i < 8; ++i) {
    const float b = bcr[obase + i];
#pragma unroll
    for (int p = 0; p < 4; ++p) acc[i][p] = b;
  }
#pragma unroll 4
  for (int c = 0; c < 64; ++c) {
    const float4 a0 = *(const float4*)&A[rbase + c * 1024];      // pos0,pos1
    const float4 a1 = *(const float4*)&A[rbase + c * 1024 + 2];  // pos2,pos3
#pragma unroll
    for (int i = 0; i < 8; ++i) {
      const float2 wc = w[(obase + i) * 64 + c];
      acc[i][0] = fmaf(wc.x, a0.x, acc[i][0]); acc[i][0] = fmaf(wc.y, a0.y, acc[i][0]);
      acc[i][1] = fmaf(wc.x, a0.z, acc[i][1]); acc[i][1] = fmaf(wc.y, a0.w, acc[i][1]);
      acc[i][2] = fmaf(wc.x, a1.x, acc[i][2]); acc[i][2] = fmaf(wc.y, a1.y, acc[i][2]);
      acc[i][3] = fmaf(wc.x, a1.z, acc[i][3]); acc[i][3] = fmaf(wc.y, a1.w, acc[i][3]);
    }
  }
  const int wb = bl * 65536 + p0 + pcol;
#pragma unroll
  for (int i = 0; i < 8; ++i) {
    *(float4*)&out0[wb + (obase + i) * 1024] =
        make_float4(acc[i][0], acc[i][1], acc[i][2], acc[i][3]);
  }
}

// ---------------- K6: LayerNorm + residual, in place on out0 ----------------
// Block = 1 image (b,l,o) of 1024 values; 256 threads x float4.
__global__ __launch_bounds__(256) void k_ln(float* __restrict__ out0,
                                            const float* __restrict__ x,
                                            const float* __restrict__ lnw,
                                            const float* __restrict__ lnb) {
  __shared__ float red[8];
  const int t = threadIdx.x;
  const int base = blockIdx.x * 1024;
  const int sp = t * 4;
  float4 v = *(const float4*)&out0[base + sp];
  float s1 = v.x + v.y + v.z + v.w;
  float s2 = v.x * v.x + v.y * v.y + v.z * v.z + v.w * v.w;
#pragma unroll
  for (int m = 1; m < 64; m <<= 1) {
    s1 += __shfl_xor(s1, m, 64);
    s2 += __shfl_xor(s2, m, 64);
  }
  if ((t & 63) == 0) { red[(t >> 6) * 2] = s1; red[(t >> 6) * 2 + 1] = s2; }
  __syncthreads();
  s1 = red[0] + red[2] + red[4] + red[6];
  s2 = red[1] + red[3] + red[5] + red[7];
  const float mu = s1 * (1.0f / 1024.0f);
  const float var = s2 * (1.0f / 1024.0f) - mu * mu;
  const float rs = rsqrtf(var + 1e-5f);
  const float4 xv = *(const float4*)&x[base + sp];
  const float4 lw = *(const float4*)&lnw[sp];
  const float4 lb = *(const float4*)&lnb[sp];
  float4 o;
  o.x = (v.x - mu) * rs * lw.x + lb.x + xv.x;
  o.y = (v.y - mu) * rs * lw.y + lb.y + xv.y;
  o.z = (v.z - mu) * rs * lw.z + lb.z + xv.z;
  o.w = (v.w - mu) * rs * lw.w + lb.w + xv.w;
  *(float4*)&out0[base + sp] = o;
}

extern "C" void kernel_launch(void* const* d_in, const int* in_sizes, int n_in,
                              void* d_out, int out_size, void* d_ws, size_t ws_size,
                              hipStream_t stream) {
  const float* x   = (const float*)d_in[0];
  const float* pl  = (const float*)d_in[1];
  const float* Wbr = (const float*)d_in[2];
  const float* Wbi = (const float*)d_in[3];
  const float* bbr = (const float*)d_in[4];
  const float* bbi = (const float*)d_in[5];
  const float* Wcr = (const float*)d_in[6];
  const float* Wci = (const float*)d_in[7];
  const float* bcr = (const float*)d_in[8];
  // d_in[9] = bc_i: dropped by taking real part
  const float* lnw = (const float*)d_in[10];
  const float* lnb = (const float*)d_in[11];

  float* out0 = (float*)d_out;
  float* out1 = (float*)d_out + NELEM;  // tail: last_hidden_out
  float2* A = (float2*)d_ws;            // 16,777,216 complex = 134 MB

  const int tail = out_size - NELEM;

  kmix_b<<<1024, 1024, 0, stream>>>(x, A, Wbr, Wbi);
  kfft_fwd<<<4096, 128, 0, stream>>>(A, pl, bbr, bbi);
  if (tail == 262144) {
    kscan<0><<<1024, 256, 0, stream>>>(A, pl, out1);  // real part only
  } else {
    kscan<1><<<1024, 256, 0, stream>>>(A, pl, out1);  // interleaved complex
  }
  kfft_inv<<<4096, 128, 0, stream>>>(A);
  kmix_cr<<<1024, 512, 0, stream>>>(A, out0, Wcr, Wci, bcr);
  k_ln<<<16384, 256, 0, stream>>>(out0, x, lnw, lnb);
}